// Round 9
// baseline (783.195 us; speedup 1.0000x reference)
//
#include <hip/hip_runtime.h>

#define N_NODES 100000
#define N_EDGES 1600000
#define N_GRAPHS 512
#define BN_EPS 1e-5f
#define NB 98          // buckets = dst>>10
#define NBLK 256       // binning blocks
#define EPB 6250       // edges per binning block (256*6250 = 1.6M)

typedef __bf16 bf16x8 __attribute__((ext_vector_type(8)));
typedef __bf16 bf16x4 __attribute__((ext_vector_type(4)));
typedef float  f32x4  __attribute__((ext_vector_type(4)));

// ---------------- merged prep: x->bf16, weights->swizzled bf16, zero pooled ----------------

__global__ void prep_kernel(const float* __restrict__ x,
                            const float* __restrict__ w1, const float* __restrict__ w2,
                            __bf16* __restrict__ xb, __bf16* __restrict__ w1S,
                            __bf16* __restrict__ w2S, float* __restrict__ pooled) {
    int b = blockIdx.x, t = threadIdx.x;
    if (b < 12500) {
        int i = b * 256 + t;                        // 3,200,000 float4 groups exactly
        float4 v = ((const float4*)x)[i];
        bf16x4 o;
        o[0] = (__bf16)v.x; o[1] = (__bf16)v.y; o[2] = (__bf16)v.z; o[3] = (__bf16)v.w;
        ((bf16x4*)xb)[i] = o;
    } else if (b < 13012) {
        int i = (b - 12500) * 256 + t;              // 131072 exactly
        int l = i >> 15, r = i & 32767;
        int k = r >> 8, n = r & 255;
        w1S[(l << 15) + (k >> 3) * 2048 + n * 8 + (k & 7)] = (__bf16)w1[i];
        int k2 = r >> 7, n2 = r & 127;
        w2S[(l << 15) + (k2 >> 3) * 1024 + n2 * 8 + (k2 & 7)] = (__bf16)w2[i];
    } else {
        int i = (b - 13012) * 256 + t;              // 16384 float4 exactly
        float4 z = {0.f, 0.f, 0.f, 0.f};
        ((float4*)pooled)[i] = z;
    }
}

// ---------------- CSR build ----------------

__global__ __launch_bounds__(256) void count_kernel(const int* __restrict__ dstv,
                                                    int* __restrict__ bh) {
    __shared__ int lh[NB];
    int t = threadIdx.x, blk = blockIdx.x;
    if (t < NB) lh[t] = 0;
    __syncthreads();
    int base = blk * EPB;
    int lim = base + EPB;
    for (int e = base + t; e < lim; e += 256) {
        atomicAdd(&lh[dstv[e] >> 10], 1);
    }
    __syncthreads();
    if (t < NB) bh[blk * NB + t] = lh[t];
}

__global__ void scan_col_kernel(const int* __restrict__ bh, int* __restrict__ offs,
                                int* __restrict__ bsz) {
    int b = blockIdx.x;
    int t = threadIdx.x;
    __shared__ int s[256];
    int v = bh[t * NB + b];
    s[t] = v; __syncthreads();
    for (int off = 1; off < 256; off <<= 1) {
        int x = (t >= off) ? s[t - off] : 0;
        __syncthreads();
        s[t] += x;
        __syncthreads();
    }
    offs[t * NB + b] = s[t] - v;   // exclusive
    if (t == 255) bsz[b] = s[255];
}

// bucket placement; bktbase recomputed in-block from bsz (98-entry scan)
__global__ __launch_bounds__(256) void bin_place_kernel(
    const int* __restrict__ srcv, const int* __restrict__ dstv,
    const int* __restrict__ offs, const int* __restrict__ bsz,
    unsigned int* __restrict__ pairs) {
    __shared__ int sb[128];
    __shared__ int lcur[NB];
    int t = threadIdx.x, blk = blockIdx.x;
    if (t < 128) sb[t] = (t < NB) ? bsz[t] : 0;
    __syncthreads();
    for (int off = 1; off < 128; off <<= 1) {
        int x = (t >= off && t < 128) ? sb[t - off] : 0;
        __syncthreads();
        if (t < 128) sb[t] += x;
        __syncthreads();
    }
    if (t < NB) lcur[t] = (sb[t] - bsz[t]) + offs[blk * NB + t];
    __syncthreads();
    int base = blk * EPB;
    int lim = base + EPB;
    for (int e = base + t; e < lim; e += 256) {
        int d = dstv[e];
        int src = srcv[e];
        int b = d >> 10;
        int p = atomicAdd(&lcur[b], 1);
        pairs[p] = ((unsigned int)(d & 1023) << 17) | (unsigned int)src;
    }
}

// one block per bucket: hist -> scan -> rowptr + place eidx + per-block degree hist
__global__ __launch_bounds__(256) void fill2_kernel(
    const unsigned int* __restrict__ pairs, const int* __restrict__ bsz,
    int* __restrict__ rowp, int* __restrict__ eidx, int* __restrict__ dbh) {
    __shared__ int sb[128];
    __shared__ int lh[1024];
    __shared__ int lsc[1024];
    __shared__ int s4[256];
    __shared__ int dh[1024];
    int b = blockIdx.x;
    int t = threadIdx.x;
    int node0 = b << 10;
    int nn = (node0 + 1024 <= N_NODES) ? 1024 : (N_NODES - node0);
    if (t < 128) sb[t] = (t < NB) ? bsz[t] : 0;
    __syncthreads();
    for (int off = 1; off < 128; off <<= 1) {
        int x = (t >= off && t < 128) ? sb[t - off] : 0;
        __syncthreads();
        if (t < 128) sb[t] += x;
        __syncthreads();
    }
    int e1 = sb[b];
    int e0 = e1 - bsz[b];
    int bb = e0;
    for (int i = t; i < 1024; i += 256) { lh[i] = 0; dh[i] = 0; }
    __syncthreads();
    for (int e = e0 + t; e < e1; e += 256) atomicAdd(&lh[pairs[e] >> 17], 1);
    __syncthreads();
    int a0 = lh[4 * t], a1 = lh[4 * t + 1], a2 = lh[4 * t + 2], a3 = lh[4 * t + 3];
    s4[t] = a0 + a1 + a2 + a3;
    __syncthreads();
    for (int off = 1; off < 256; off <<= 1) {
        int x = (t >= off) ? s4[t - off] : 0;
        __syncthreads();
        s4[t] += x;
        __syncthreads();
    }
    int base4 = s4[t] - (a0 + a1 + a2 + a3);
    lsc[4 * t]     = base4;
    lsc[4 * t + 1] = base4 + a0;
    lsc[4 * t + 2] = base4 + a0 + a1;
    lsc[4 * t + 3] = base4 + a0 + a1 + a2;
    __syncthreads();
    int total = e1 - e0;
    for (int i = t; i < nn; i += 256) {
        rowp[node0 + i] = bb + lsc[i];
        int dg = ((i < 1023) ? lsc[i + 1] : total) - lsc[i];
        if (dg > 1023) dg = 1023;
        atomicAdd(&dh[dg], 1);
    }
    if (b == NB - 1 && t == 0) rowp[N_NODES] = N_EDGES;
    for (int i = t; i < 1024; i += 256) lh[i] = bb + lsc[i];
    __syncthreads();
    for (int e = e0 + t; e < e1; e += 256) {
        unsigned int u = pairs[e];
        int ld = (int)(u >> 17);
        int src = (int)(u & 0x1FFFF);
        int p = atomicAdd(&lh[ld], 1);
        eidx[p] = src;
    }
    for (int j = t; j < 1024; j += 256) dbh[b * 1024 + j] = dh[j];
}

__global__ void dscan_col_kernel(const int* __restrict__ dbh, int* __restrict__ doffs,
                                 int* __restrict__ colsz) {
    __shared__ int s[128];
    int bin = blockIdx.x, t = threadIdx.x;
    int v = (t < NB) ? dbh[t * 1024 + bin] : 0;
    s[t] = v; __syncthreads();
    for (int off = 1; off < 128; off <<= 1) {
        int x = (t >= off) ? s[t - off] : 0;
        __syncthreads();
        s[t] += x;
        __syncthreads();
    }
    if (t < NB) doffs[t * 1024 + bin] = s[t] - v;
    if (t == 127) colsz[bin] = s[127];
}

__global__ __launch_bounds__(256) void dplace2_kernel(const int* __restrict__ rowp,
                                                      const int* __restrict__ doffs,
                                                      const int* __restrict__ colsz,
                                                      int* __restrict__ perm) {
    __shared__ int a[1024];
    __shared__ int s4[256];
    __shared__ int lcur[1024];
    int b = blockIdx.x, t = threadIdx.x;
    for (int j = 0; j < 4; j++) a[4 * t + j] = colsz[1023 - (4 * t + j)];
    __syncthreads();
    int a0 = a[4 * t], a1 = a[4 * t + 1], a2 = a[4 * t + 2], a3 = a[4 * t + 3];
    s4[t] = a0 + a1 + a2 + a3;
    __syncthreads();
    for (int off = 1; off < 256; off <<= 1) {
        int x = (t >= off) ? s4[t - off] : 0;
        __syncthreads();
        s4[t] += x;
        __syncthreads();
    }
    int base4 = s4[t] - (a0 + a1 + a2 + a3);
    int ex0 = base4;
    int ex1 = base4 + a0;
    int ex2 = base4 + a0 + a1;
    int ex3 = base4 + a0 + a1 + a2;
    lcur[1023 - (4 * t)]     = ex0 + doffs[b * 1024 + (1023 - 4 * t)];
    lcur[1023 - (4 * t + 1)] = ex1 + doffs[b * 1024 + (1023 - (4 * t + 1))];
    lcur[1023 - (4 * t + 2)] = ex2 + doffs[b * 1024 + (1023 - (4 * t + 2))];
    lcur[1023 - (4 * t + 3)] = ex3 + doffs[b * 1024 + (1023 - (4 * t + 3))];
    __syncthreads();
    int node0 = b << 10;
    int nn = (node0 + 1024 <= N_NODES) ? 1024 : (N_NODES - node0);
    for (int i = t; i < nn; i += 256) {
        int node = node0 + i;
        int dg = rowp[node + 1] - rowp[node];
        if (dg > 1023) dg = 1023;
        int pos = atomicAdd(&lcur[dg], 1);
        perm[pos] = node;
    }
}

// ---------------- fully fused GIN layer ----------------
// Split-K streaming: 64x128 h-tile (16 KB LDS) reused across two K-halves;
// phase-2 accumulates its 8 output tiles in registers across halves.
// Per-wave RAW only -> no barriers; waves flow independently.

__global__ __launch_bounds__(256, 4) void gin_layer(
    const __bf16* __restrict__ xin, const int* __restrict__ rowptr, const int* __restrict__ eidx,
    const int* __restrict__ perm,
    const __bf16* __restrict__ w1S, const __bf16* __restrict__ w2S,
    const float* __restrict__ b1, const float* __restrict__ g1, const float* __restrict__ bb1,
    const float* __restrict__ m1, const float* __restrict__ v1,
    const float* __restrict__ b2, const float* __restrict__ g2, const float* __restrict__ bb2,
    const float* __restrict__ m2, const float* __restrict__ v2,
    const float* __restrict__ gin_eps, int layer, __bf16* __restrict__ xout)
{
    __shared__ __align__(16) __bf16 hs[64 * 128];   // 16 KB
    int tid = threadIdx.x;
    int wv = tid >> 6, lane = tid & 63;
    int bm = blockIdx.x * 64 + wv * 16;
    int m = lane & 15, q = lane >> 4;
    int gidx = bm + m;
    bool valid = gidx < N_NODES;
    int prow = valid ? perm[gidx] : 0;
    float eps1 = 1.0f + gin_eps[layer];
    int qo = q * 8;

    // ---- phase 0: per-lane register gather ----
    const __bf16* base = xin + (size_t)prow * 128 + qo;
    float acc[32];
    {
        bf16x8 s0 = *(const bf16x8*)(base);
        bf16x8 s1 = *(const bf16x8*)(base + 32);
        bf16x8 s2 = *(const bf16x8*)(base + 64);
        bf16x8 s3 = *(const bf16x8*)(base + 96);
        #pragma unroll
        for (int j = 0; j < 8; j++) {
            acc[j]      = eps1 * (float)s0[j];
            acc[8 + j]  = eps1 * (float)s1[j];
            acc[16 + j] = eps1 * (float)s2[j];
            acc[24 + j] = eps1 * (float)s3[j];
        }
    }
    int e0 = rowptr[prow];
    int e1 = valid ? rowptr[prow + 1] : e0;
    int e = e0;
    for (; e + 4 <= e1; e += 4) {
        int i0 = eidx[e], i1 = eidx[e + 1], i2 = eidx[e + 2], i3 = eidx[e + 3];
        const __bf16* p0 = xin + (size_t)i0 * 128 + qo;
        const __bf16* p1 = xin + (size_t)i1 * 128 + qo;
        const __bf16* p2 = xin + (size_t)i2 * 128 + qo;
        const __bf16* p3 = xin + (size_t)i3 * 128 + qo;
        bf16x8 v0[4], v1r[4], v2r[4], v3r[4];
        #pragma unroll
        for (int k = 0; k < 4; k++) {
            v0[k]  = *(const bf16x8*)(p0 + k * 32);
            v1r[k] = *(const bf16x8*)(p1 + k * 32);
            v2r[k] = *(const bf16x8*)(p2 + k * 32);
            v3r[k] = *(const bf16x8*)(p3 + k * 32);
        }
        #pragma unroll
        for (int k = 0; k < 4; k++) {
            #pragma unroll
            for (int j = 0; j < 8; j++) {
                acc[k * 8 + j] += ((float)v0[k][j] + (float)v1r[k][j])
                                + ((float)v2r[k][j] + (float)v3r[k][j]);
            }
        }
    }
    for (; e < e1; ++e) {
        const __bf16* p0 = xin + (size_t)eidx[e] * 128 + qo;
        bf16x8 a0 = *(const bf16x8*)(p0);
        bf16x8 a1 = *(const bf16x8*)(p0 + 32);
        bf16x8 a2 = *(const bf16x8*)(p0 + 64);
        bf16x8 a3 = *(const bf16x8*)(p0 + 96);
        #pragma unroll
        for (int j = 0; j < 8; j++) {
            acc[j]      += (float)a0[j];
            acc[8 + j]  += (float)a1[j];
            acc[16 + j] += (float)a2[j];
            acc[24 + j] += (float)a3[j];
        }
    }

    bf16x8 af[4];
    #pragma unroll
    for (int ks = 0; ks < 4; ks++) {
        #pragma unroll
        for (int j = 0; j < 8; j++) af[ks][j] = (__bf16)acc[ks * 8 + j];
    }

    const __bf16* pB  = w1S + q * 2048 + m * 8;
    const __bf16* pB2 = w2S + q * 1024 + m * 8;
    int rq = q * 4;
    int wrow0 = wv * 16;
    int rowr = wrow0 + m;

    f32x4 acc2[8];
    #pragma unroll
    for (int i = 0; i < 8; i++) acc2[i] = {0.f, 0.f, 0.f, 0.f};

    #pragma unroll
    for (int h = 0; h < 2; h++) {
        // ---- phase 1 (half h): MFMA1 + bn1 + relu -> 64x128 LDS tile ----
        for (int nt = 0; nt < 8; nt++) {
            f32x4 o = {0.f, 0.f, 0.f, 0.f};
            #pragma unroll
            for (int ks = 0; ks < 4; ks++) {
                bf16x8 bfrag = *(const bf16x8*)(pB + (h * 8 + nt) * 128 + ks * 8192);
                o = __builtin_amdgcn_mfma_f32_16x16x32_bf16(af[ks], bfrag, o, 0, 0, 0);
            }
            int n = h * 128 + nt * 16 + m;
            float s = g1[n] * rsqrtf(v1[n] + BN_EPS);
            float cc = (b1[n] - m1[n]) * s + bb1[n];
            #pragma unroll
            for (int r2 = 0; r2 < 4; r2++) {
                int row = wrow0 + rq + r2;
                float z = o[r2] * s + cc;
                hs[(row << 7) + ((nt * 16 + m + (row << 3)) & 127)] = (__bf16)fmaxf(z, 0.0f);
            }
        }
        // ---- phase 2 partial: this half's K contribution for all 8 n-tiles ----
        bf16x8 af2[4];
        #pragma unroll
        for (int ks = 0; ks < 4; ks++) {
            int nr = (ks * 32 + qo + (rowr << 3)) & 127;
            af2[ks] = *(const bf16x8*)&hs[(rowr << 7) + nr];
        }
        #pragma unroll
        for (int nt2 = 0; nt2 < 8; nt2++) {
            #pragma unroll
            for (int ks = 0; ks < 4; ks++) {
                bf16x8 bfrag = *(const bf16x8*)(pB2 + nt2 * 128 + (h * 4 + ks) * 4096);
                acc2[nt2] = __builtin_amdgcn_mfma_f32_16x16x32_bf16(af2[ks], bfrag, acc2[nt2], 0, 0, 0);
            }
        }
    }

    // ---- epilogue: bn2 + relu -> xout ----
    int op[4]; bool ov[4];
    #pragma unroll
    for (int r2 = 0; r2 < 4; r2++) {
        int gi = bm + rq + r2;
        ov[r2] = gi < N_NODES;
        op[r2] = ov[r2] ? perm[gi] : 0;
    }
    for (int nt2 = 0; nt2 < 8; nt2++) {
        int n = nt2 * 16 + m;
        float s = g2[n] * rsqrtf(v2[n] + BN_EPS);
        float cc = (b2[n] - m2[n]) * s + bb2[n];
        #pragma unroll
        for (int r2 = 0; r2 < 4; r2++) {
            if (ov[r2]) {
                float z = acc2[nt2][r2] * s + cc;
                xout[(size_t)op[r2] * 128 + n] = (__bf16)fmaxf(z, 0.0f);
            }
        }
    }
}

// ---------------- pooling + head ----------------

__global__ void pool_kernel(const __bf16* __restrict__ xb, const int* __restrict__ batch,
                            float* __restrict__ pooled) {
    int c = threadIdx.x;
    int n0 = blockIdx.x * 64;
    if (n0 >= N_NODES) return;
    int cur = batch[n0];
    float acc = 0.0f;
    int nend = (n0 + 64 < N_NODES) ? n0 + 64 : N_NODES;
    for (int node = n0; node < nend; node++) {
        int b = batch[node];
        if (b != cur) {
            unsafeAtomicAdd(&pooled[cur * 128 + c], acc);
            acc = 0.0f; cur = b;
        }
        acc += (float)xb[(size_t)node * 128 + c];
    }
    unsafeAtomicAdd(&pooled[cur * 128 + c], acc);
}

__global__ void final_kernel(const float* __restrict__ pooled,
                             const float* __restrict__ lw1, const float* __restrict__ lb1,
                             const float* __restrict__ g3, const float* __restrict__ b3,
                             const float* __restrict__ m3, const float* __restrict__ v3,
                             const float* __restrict__ lw2, const float* __restrict__ lb2,
                             float* __restrict__ out) {
    int gid = blockIdx.x;
    int t = threadIdx.x;
    __shared__ float p[128], hsf[128], lg[10];
    p[t] = pooled[gid * 128 + t];
    __syncthreads();
    float z = lb1[t];
    #pragma unroll 4
    for (int k = 0; k < 128; k++) z += p[k] * lw1[k * 128 + t];
    float h = (z - m3[t]) * rsqrtf(v3[t] + BN_EPS) * g3[t] + b3[t];
    hsf[t] = fmaxf(h, 0.0f);
    __syncthreads();
    if (t < 10) {
        float o = lb2[t];
        #pragma unroll 4
        for (int k = 0; k < 128; k++) o += hsf[k] * lw2[k * 10 + t];
        lg[t] = o;
    }
    __syncthreads();
    if (t < 10) {
        float mx = lg[0];
        for (int j = 1; j < 10; j++) mx = fmaxf(mx, lg[j]);
        float sum = 0.0f;
        for (int j = 0; j < 10; j++) sum += expf(lg[j] - mx);
        out[gid * 10 + t] = lg[t] - mx - logf(sum);
    }
}

// ---------------- launch ----------------

extern "C" void kernel_launch(void* const* d_in, const int* in_sizes, int n_in,
                              void* d_out, int out_size, void* d_ws, size_t ws_size,
                              hipStream_t stream) {
    (void)in_sizes; (void)n_in; (void)out_size; (void)ws_size;
    const float* x      = (const float*)d_in[0];
    const int*   ei     = (const int*)d_in[1];
    const int*   srcv   = ei;
    const int*   dstv   = ei + N_EDGES;
    const int*   batch  = (const int*)d_in[2];
    const float* w1     = (const float*)d_in[3];
    const float* b1     = (const float*)d_in[4];
    const float* bn1_g  = (const float*)d_in[5];
    const float* bn1_b  = (const float*)d_in[6];
    const float* bn1_m  = (const float*)d_in[7];
    const float* bn1_v  = (const float*)d_in[8];
    const float* geps   = (const float*)d_in[9];
    const float* w2     = (const float*)d_in[10];
    const float* b2     = (const float*)d_in[11];
    const float* bn2_g  = (const float*)d_in[12];
    const float* bn2_b  = (const float*)d_in[13];
    const float* bn2_m  = (const float*)d_in[14];
    const float* bn2_v  = (const float*)d_in[15];
    const float* lw1    = (const float*)d_in[16];
    const float* lb1    = (const float*)d_in[17];
    const float* g3     = (const float*)d_in[18];
    const float* b3     = (const float*)d_in[19];
    const float* m3     = (const float*)d_in[20];
    const float* v3     = (const float*)d_in[21];
    const float* lw2    = (const float*)d_in[22];
    const float* lb2    = (const float*)d_in[23];
    float* out = (float*)d_out;

    char* ws = (char*)d_ws;
    __bf16* xb    = (__bf16*)(ws + 0);                 // 25.6 MB (ping)
    __bf16* xb2   = (__bf16*)(ws + 25600000);          // 25.6 MB (pong)
    unsigned int* pairs = (unsigned int*)(ws + 51200000);   // 6.4 MB
    int*    bh    = (int*)   (ws + 57600000);          // 100352
    int*    offs  = (int*)   (ws + 57700352);          // 100352
    int*    bsz   = (int*)   (ws + 57800704);          // 512
    int*    dbh   = (int*)   (ws + 57801216);          // 401408
    int*    doffs = (int*)   (ws + 58202624);          // 401408
    int*    colsz = (int*)   (ws + 58604032);          // 4096
    __bf16* w1S   = (__bf16*)(ws + 76800000);
    __bf16* w2S   = (__bf16*)(ws + 77062144);
    int*    rowp  = (int*)   (ws + 77324288);          // 400004
    int*    perm  = (int*)   (ws + 77724416);          // 400000
    int*    eidx  = (int*)   (ws + 78124416);          // 6.4 MB
    float*  pooled= (float*) (ws + 84524416);          // 262144

    prep_kernel<<<13076, 256, 0, stream>>>(x, w1, w2, xb, w1S, w2S, pooled);

    // CSR build
    count_kernel<<<NBLK, 256, 0, stream>>>(dstv, bh);
    scan_col_kernel<<<NB, 256, 0, stream>>>(bh, offs, bsz);
    bin_place_kernel<<<NBLK, 256, 0, stream>>>(srcv, dstv, offs, bsz, pairs);
    fill2_kernel<<<NB, 256, 0, stream>>>(pairs, bsz, rowp, eidx, dbh);

    // degree sort (descending), deterministic
    dscan_col_kernel<<<1024, 128, 0, stream>>>(dbh, doffs, colsz);
    dplace2_kernel<<<NB, 256, 0, stream>>>(rowp, doffs, colsz, perm);

    int mblocks = (N_NODES + 63) / 64;  // 1563
    __bf16* xin = xb;
    __bf16* xout = xb2;
    for (int l = 0; l < 4; l++) {
        gin_layer<<<mblocks, 256, 0, stream>>>(
            xin, rowp, eidx, perm, w1S + l * 32768, w2S + l * 32768,
            b1 + l * 256, bn1_g + l * 256, bn1_b + l * 256, bn1_m + l * 256, bn1_v + l * 256,
            b2 + l * 128, bn2_g + l * 128, bn2_b + l * 128, bn2_m + l * 128, bn2_v + l * 128,
            geps, l, xout);
        __bf16* t = xin; xin = xout; xout = t;
    }
    // after 4 layers, final x is in xin == xb

    pool_kernel<<<(N_NODES + 63) / 64, 128, 0, stream>>>(xin, batch, pooled);
    final_kernel<<<N_GRAPHS, 128, 0, stream>>>(pooled, lw1, lb1, g3, b3, m3, v3, lw2, lb2, out);
}

// Round 10
// 641.617 us; speedup vs baseline: 1.2207x; 1.2207x over previous
//
#include <hip/hip_runtime.h>

#define N_NODES 100000
#define N_EDGES 1600000
#define N_GRAPHS 512
#define BN_EPS 1e-5f
#define NB 98          // buckets = dst>>10
#define NBLK 256       // binning blocks
#define EPB 6250       // edges per binning block (256*6250 = 1.6M)

typedef __bf16 bf16x8 __attribute__((ext_vector_type(8)));
typedef __bf16 bf16x4 __attribute__((ext_vector_type(4)));
typedef float  f32x4  __attribute__((ext_vector_type(4)));

// ---------------- merged prep: x->bf16, weights->swizzled bf16, zero pooled ----------------

__global__ void prep_kernel(const float* __restrict__ x,
                            const float* __restrict__ w1, const float* __restrict__ w2,
                            __bf16* __restrict__ xb, __bf16* __restrict__ w1S,
                            __bf16* __restrict__ w2S, float* __restrict__ pooled) {
    int b = blockIdx.x, t = threadIdx.x;
    if (b < 12500) {
        int i = b * 256 + t;                        // 3,200,000 float4 groups exactly
        float4 v = ((const float4*)x)[i];
        bf16x4 o;
        o[0] = (__bf16)v.x; o[1] = (__bf16)v.y; o[2] = (__bf16)v.z; o[3] = (__bf16)v.w;
        ((bf16x4*)xb)[i] = o;
    } else if (b < 13012) {
        int i = (b - 12500) * 256 + t;              // 131072 exactly
        int l = i >> 15, r = i & 32767;
        int k = r >> 8, n = r & 255;
        w1S[(l << 15) + (k >> 3) * 2048 + n * 8 + (k & 7)] = (__bf16)w1[i];
        int k2 = r >> 7, n2 = r & 127;
        w2S[(l << 15) + (k2 >> 3) * 1024 + n2 * 8 + (k2 & 7)] = (__bf16)w2[i];
    } else {
        int i = (b - 13012) * 256 + t;              // 16384 float4 exactly
        float4 z = {0.f, 0.f, 0.f, 0.f};
        ((float4*)pooled)[i] = z;
    }
}

// ---------------- CSR build ----------------

__global__ __launch_bounds__(256) void count_kernel(const int* __restrict__ dstv,
                                                    int* __restrict__ bh) {
    __shared__ int lh[NB];
    int t = threadIdx.x, blk = blockIdx.x;
    if (t < NB) lh[t] = 0;
    __syncthreads();
    int base = blk * EPB;
    int lim = base + EPB;
    for (int e = base + t; e < lim; e += 256) {
        atomicAdd(&lh[dstv[e] >> 10], 1);
    }
    __syncthreads();
    if (t < NB) bh[blk * NB + t] = lh[t];
}

__global__ void scan_col_kernel(const int* __restrict__ bh, int* __restrict__ offs,
                                int* __restrict__ bsz) {
    int b = blockIdx.x;
    int t = threadIdx.x;
    __shared__ int s[256];
    int v = bh[t * NB + b];
    s[t] = v; __syncthreads();
    for (int off = 1; off < 256; off <<= 1) {
        int x = (t >= off) ? s[t - off] : 0;
        __syncthreads();
        s[t] += x;
        __syncthreads();
    }
    offs[t * NB + b] = s[t] - v;   // exclusive
    if (t == 255) bsz[b] = s[255];
}

// bucket placement; bktbase recomputed in-block from bsz (98-entry scan)
__global__ __launch_bounds__(256) void bin_place_kernel(
    const int* __restrict__ srcv, const int* __restrict__ dstv,
    const int* __restrict__ offs, const int* __restrict__ bsz,
    unsigned int* __restrict__ pairs) {
    __shared__ int sb[128];
    __shared__ int lcur[NB];
    int t = threadIdx.x, blk = blockIdx.x;
    if (t < 128) sb[t] = (t < NB) ? bsz[t] : 0;
    __syncthreads();
    for (int off = 1; off < 128; off <<= 1) {
        int x = (t >= off && t < 128) ? sb[t - off] : 0;
        __syncthreads();
        if (t < 128) sb[t] += x;
        __syncthreads();
    }
    if (t < NB) lcur[t] = (sb[t] - bsz[t]) + offs[blk * NB + t];
    __syncthreads();
    int base = blk * EPB;
    int lim = base + EPB;
    for (int e = base + t; e < lim; e += 256) {
        int d = dstv[e];
        int src = srcv[e];
        int b = d >> 10;
        int p = atomicAdd(&lcur[b], 1);
        pairs[p] = ((unsigned int)(d & 1023) << 17) | (unsigned int)src;
    }
}

// one block per bucket: hist -> scan -> rowptr + place eidx + per-block degree hist
__global__ __launch_bounds__(256) void fill2_kernel(
    const unsigned int* __restrict__ pairs, const int* __restrict__ bsz,
    int* __restrict__ rowp, int* __restrict__ eidx, int* __restrict__ dbh) {
    __shared__ int sb[128];
    __shared__ int lh[1024];
    __shared__ int lsc[1024];
    __shared__ int s4[256];
    __shared__ int dh[1024];
    int b = blockIdx.x;
    int t = threadIdx.x;
    int node0 = b << 10;
    int nn = (node0 + 1024 <= N_NODES) ? 1024 : (N_NODES - node0);
    if (t < 128) sb[t] = (t < NB) ? bsz[t] : 0;
    __syncthreads();
    for (int off = 1; off < 128; off <<= 1) {
        int x = (t >= off && t < 128) ? sb[t - off] : 0;
        __syncthreads();
        if (t < 128) sb[t] += x;
        __syncthreads();
    }
    int e1 = sb[b];
    int e0 = e1 - bsz[b];
    int bb = e0;
    for (int i = t; i < 1024; i += 256) { lh[i] = 0; dh[i] = 0; }
    __syncthreads();
    for (int e = e0 + t; e < e1; e += 256) atomicAdd(&lh[pairs[e] >> 17], 1);
    __syncthreads();
    int a0 = lh[4 * t], a1 = lh[4 * t + 1], a2 = lh[4 * t + 2], a3 = lh[4 * t + 3];
    s4[t] = a0 + a1 + a2 + a3;
    __syncthreads();
    for (int off = 1; off < 256; off <<= 1) {
        int x = (t >= off) ? s4[t - off] : 0;
        __syncthreads();
        s4[t] += x;
        __syncthreads();
    }
    int base4 = s4[t] - (a0 + a1 + a2 + a3);
    lsc[4 * t]     = base4;
    lsc[4 * t + 1] = base4 + a0;
    lsc[4 * t + 2] = base4 + a0 + a1;
    lsc[4 * t + 3] = base4 + a0 + a1 + a2;
    __syncthreads();
    int total = e1 - e0;
    for (int i = t; i < nn; i += 256) {
        rowp[node0 + i] = bb + lsc[i];
        int dg = ((i < 1023) ? lsc[i + 1] : total) - lsc[i];
        if (dg > 1023) dg = 1023;
        atomicAdd(&dh[dg], 1);
    }
    if (b == NB - 1 && t == 0) rowp[N_NODES] = N_EDGES;
    for (int i = t; i < 1024; i += 256) lh[i] = bb + lsc[i];
    __syncthreads();
    for (int e = e0 + t; e < e1; e += 256) {
        unsigned int u = pairs[e];
        int ld = (int)(u >> 17);
        int src = (int)(u & 0x1FFFF);
        int p = atomicAdd(&lh[ld], 1);
        eidx[p] = src;
    }
    for (int j = t; j < 1024; j += 256) dbh[b * 1024 + j] = dh[j];
}

__global__ void dscan_col_kernel(const int* __restrict__ dbh, int* __restrict__ doffs,
                                 int* __restrict__ colsz) {
    __shared__ int s[128];
    int bin = blockIdx.x, t = threadIdx.x;
    int v = (t < NB) ? dbh[t * 1024 + bin] : 0;
    s[t] = v; __syncthreads();
    for (int off = 1; off < 128; off <<= 1) {
        int x = (t >= off) ? s[t - off] : 0;
        __syncthreads();
        s[t] += x;
        __syncthreads();
    }
    if (t < NB) doffs[t * 1024 + bin] = s[t] - v;
    if (t == 127) colsz[bin] = s[127];
}

__global__ __launch_bounds__(256) void dplace2_kernel(const int* __restrict__ rowp,
                                                      const int* __restrict__ doffs,
                                                      const int* __restrict__ colsz,
                                                      int* __restrict__ perm) {
    __shared__ int a[1024];
    __shared__ int s4[256];
    __shared__ int lcur[1024];
    int b = blockIdx.x, t = threadIdx.x;
    for (int j = 0; j < 4; j++) a[4 * t + j] = colsz[1023 - (4 * t + j)];
    __syncthreads();
    int a0 = a[4 * t], a1 = a[4 * t + 1], a2 = a[4 * t + 2], a3 = a[4 * t + 3];
    s4[t] = a0 + a1 + a2 + a3;
    __syncthreads();
    for (int off = 1; off < 256; off <<= 1) {
        int x = (t >= off) ? s4[t - off] : 0;
        __syncthreads();
        s4[t] += x;
        __syncthreads();
    }
    int base4 = s4[t] - (a0 + a1 + a2 + a3);
    int ex0 = base4;
    int ex1 = base4 + a0;
    int ex2 = base4 + a0 + a1;
    int ex3 = base4 + a0 + a1 + a2;
    lcur[1023 - (4 * t)]     = ex0 + doffs[b * 1024 + (1023 - 4 * t)];
    lcur[1023 - (4 * t + 1)] = ex1 + doffs[b * 1024 + (1023 - (4 * t + 1))];
    lcur[1023 - (4 * t + 2)] = ex2 + doffs[b * 1024 + (1023 - (4 * t + 2))];
    lcur[1023 - (4 * t + 3)] = ex3 + doffs[b * 1024 + (1023 - (4 * t + 3))];
    __syncthreads();
    int node0 = b << 10;
    int nn = (node0 + 1024 <= N_NODES) ? 1024 : (N_NODES - node0);
    for (int i = t; i < nn; i += 256) {
        int node = node0 + i;
        int dg = rowp[node + 1] - rowp[node];
        if (dg > 1023) dg = 1023;
        int pos = atomicAdd(&lcur[dg], 1);
        perm[pos] = node;
    }
}

// ---------------- fully fused GIN layer (R7 structure + pipelined gather) ----------------
// Gather is a 2-edge software pipeline: next stage's 8x16B loads are independent
// of the current accumulate -> ~8 loads in flight per lane. Per-wave LDS tile,
// no barriers.

__global__ __launch_bounds__(256, 4) void gin_layer(
    const __bf16* __restrict__ xin, const int* __restrict__ rowptr, const int* __restrict__ eidx,
    const int* __restrict__ perm,
    const __bf16* __restrict__ w1S, const __bf16* __restrict__ w2S,
    const float* __restrict__ b1, const float* __restrict__ g1, const float* __restrict__ bb1,
    const float* __restrict__ m1, const float* __restrict__ v1,
    const float* __restrict__ b2, const float* __restrict__ g2, const float* __restrict__ bb2,
    const float* __restrict__ m2, const float* __restrict__ v2,
    const float* __restrict__ gin_eps, int layer, __bf16* __restrict__ xout)
{
    __shared__ __align__(16) __bf16 hs[64 * 264];   // 33.8 KB, stride 264
    int tid = threadIdx.x;
    int wv = tid >> 6, lane = tid & 63;
    int bm = blockIdx.x * 64 + wv * 16;
    int m = lane & 15, q = lane >> 4;
    int gidx = bm + m;
    bool valid = gidx < N_NODES;
    int prow = valid ? perm[gidx] : 0;
    float eps1 = 1.0f + gin_eps[layer];
    int qo = q * 8;

    // ---- phase 0: pipelined per-lane register gather ----
    const __bf16* base = xin + (size_t)prow * 128 + qo;
    float acc[32];
    {
        bf16x8 s0 = *(const bf16x8*)(base);
        bf16x8 s1 = *(const bf16x8*)(base + 32);
        bf16x8 s2 = *(const bf16x8*)(base + 64);
        bf16x8 s3 = *(const bf16x8*)(base + 96);
        #pragma unroll
        for (int j = 0; j < 8; j++) {
            acc[j]      = eps1 * (float)s0[j];
            acc[8 + j]  = eps1 * (float)s1[j];
            acc[16 + j] = eps1 * (float)s2[j];
            acc[24 + j] = eps1 * (float)s3[j];
        }
    }
    int e0 = rowptr[prow];
    int e1 = valid ? rowptr[prow + 1] : e0;
    int e = e0;
    bf16x8 cur[2][4];
    bool have = (e + 2 <= e1);
    if (have) {
        int i0 = eidx[e], i1 = eidx[e + 1];
        const __bf16* p0 = xin + (size_t)i0 * 128 + qo;
        const __bf16* p1 = xin + (size_t)i1 * 128 + qo;
        #pragma unroll
        for (int k = 0; k < 4; k++) {
            cur[0][k] = *(const bf16x8*)(p0 + k * 32);
            cur[1][k] = *(const bf16x8*)(p1 + k * 32);
        }
        e += 2;
    }
    while (e + 2 <= e1) {
        int i0 = eidx[e], i1 = eidx[e + 1];
        const __bf16* p0 = xin + (size_t)i0 * 128 + qo;
        const __bf16* p1 = xin + (size_t)i1 * 128 + qo;
        bf16x8 nxt[2][4];
        #pragma unroll
        for (int k = 0; k < 4; k++) {
            nxt[0][k] = *(const bf16x8*)(p0 + k * 32);
            nxt[1][k] = *(const bf16x8*)(p1 + k * 32);
        }
        #pragma unroll
        for (int k = 0; k < 4; k++) {
            #pragma unroll
            for (int j = 0; j < 8; j++)
                acc[k * 8 + j] += (float)cur[0][k][j] + (float)cur[1][k][j];
        }
        #pragma unroll
        for (int k = 0; k < 4; k++) {
            cur[0][k] = nxt[0][k];
            cur[1][k] = nxt[1][k];
        }
        e += 2;
    }
    if (have) {
        #pragma unroll
        for (int k = 0; k < 4; k++) {
            #pragma unroll
            for (int j = 0; j < 8; j++)
                acc[k * 8 + j] += (float)cur[0][k][j] + (float)cur[1][k][j];
        }
    }
    if (e < e1) {
        const __bf16* p0 = xin + (size_t)eidx[e] * 128 + qo;
        #pragma unroll
        for (int k = 0; k < 4; k++) {
            bf16x8 a0 = *(const bf16x8*)(p0 + k * 32);
            #pragma unroll
            for (int j = 0; j < 8; j++) acc[k * 8 + j] += (float)a0[j];
        }
    }

    bf16x8 af[4];
    #pragma unroll
    for (int ks = 0; ks < 4; ks++) {
        #pragma unroll
        for (int j = 0; j < 8; j++) af[ks][j] = (__bf16)acc[ks * 8 + j];
    }

    // ---- phase 1: MFMA1 + bn1 + relu -> per-wave LDS tile (16 x 256) ----
    const __bf16* pB = w1S + q * 2048 + m * 8;
    int rq = q * 4;
    int wrow0 = wv * 16;
    for (int nt = 0; nt < 16; nt++) {
        f32x4 o = {0.f, 0.f, 0.f, 0.f};
        #pragma unroll
        for (int ks = 0; ks < 4; ks++) {
            bf16x8 bfrag = *(const bf16x8*)(pB + nt * 128 + ks * 8192);
            o = __builtin_amdgcn_mfma_f32_16x16x32_bf16(af[ks], bfrag, o, 0, 0, 0);
        }
        int n = nt * 16 + m;
        float s = g1[n] * rsqrtf(v1[n] + BN_EPS);
        float cc = (b1[n] - m1[n]) * s + bb1[n];
        #pragma unroll
        for (int r2 = 0; r2 < 4; r2++) {
            float z = o[r2] * s + cc;
            hs[(wrow0 + rq + r2) * 264 + n] = (__bf16)fmaxf(z, 0.0f);
        }
    }

    int op[4]; bool ov[4];
    #pragma unroll
    for (int r2 = 0; r2 < 4; r2++) {
        int gi = bm + rq + r2;
        ov[r2] = gi < N_NODES;
        op[r2] = ov[r2] ? perm[gi] : 0;
    }

    // ---- phase 2: MFMA2 + bn2 + relu -> xout ----
    bf16x8 af2[8];
    #pragma unroll
    for (int ks = 0; ks < 8; ks++)
        af2[ks] = *(const bf16x8*)&hs[(wrow0 + m) * 264 + ks * 32 + qo];

    const __bf16* pB2 = w2S + q * 1024 + m * 8;
    for (int nt = 0; nt < 8; nt++) {
        f32x4 o = {0.f, 0.f, 0.f, 0.f};
        #pragma unroll
        for (int ks = 0; ks < 8; ks++) {
            bf16x8 bfrag = *(const bf16x8*)(pB2 + nt * 128 + ks * 4096);
            o = __builtin_amdgcn_mfma_f32_16x16x32_bf16(af2[ks], bfrag, o, 0, 0, 0);
        }
        int n = nt * 16 + m;
        float s = g2[n] * rsqrtf(v2[n] + BN_EPS);
        float cc = (b2[n] - m2[n]) * s + bb2[n];
        #pragma unroll
        for (int r2 = 0; r2 < 4; r2++) {
            if (ov[r2]) {
                float z = o[r2] * s + cc;
                xout[(size_t)op[r2] * 128 + n] = (__bf16)fmaxf(z, 0.0f);
            }
        }
    }
}

// ---------------- pooling + head ----------------

__global__ void pool_kernel(const __bf16* __restrict__ xb, const int* __restrict__ batch,
                            float* __restrict__ pooled) {
    int c = threadIdx.x;
    int n0 = blockIdx.x * 64;
    if (n0 >= N_NODES) return;
    int cur = batch[n0];
    float acc = 0.0f;
    int nend = (n0 + 64 < N_NODES) ? n0 + 64 : N_NODES;
    for (int node = n0; node < nend; node++) {
        int b = batch[node];
        if (b != cur) {
            unsafeAtomicAdd(&pooled[cur * 128 + c], acc);
            acc = 0.0f; cur = b;
        }
        acc += (float)xb[(size_t)node * 128 + c];
    }
    unsafeAtomicAdd(&pooled[cur * 128 + c], acc);
}

__global__ void final_kernel(const float* __restrict__ pooled,
                             const float* __restrict__ lw1, const float* __restrict__ lb1,
                             const float* __restrict__ g3, const float* __restrict__ b3,
                             const float* __restrict__ m3, const float* __restrict__ v3,
                             const float* __restrict__ lw2, const float* __restrict__ lb2,
                             float* __restrict__ out) {
    int gid = blockIdx.x;
    int t = threadIdx.x;
    __shared__ float p[128], hsf[128], lg[10];
    p[t] = pooled[gid * 128 + t];
    __syncthreads();
    float z = lb1[t];
    #pragma unroll 4
    for (int k = 0; k < 128; k++) z += p[k] * lw1[k * 128 + t];
    float h = (z - m3[t]) * rsqrtf(v3[t] + BN_EPS) * g3[t] + b3[t];
    hsf[t] = fmaxf(h, 0.0f);
    __syncthreads();
    if (t < 10) {
        float o = lb2[t];
        #pragma unroll 4
        for (int k = 0; k < 128; k++) o += hsf[k] * lw2[k * 10 + t];
        lg[t] = o;
    }
    __syncthreads();
    if (t < 10) {
        float mx = lg[0];
        for (int j = 1; j < 10; j++) mx = fmaxf(mx, lg[j]);
        float sum = 0.0f;
        for (int j = 0; j < 10; j++) sum += expf(lg[j] - mx);
        out[gid * 10 + t] = lg[t] - mx - logf(sum);
    }
}

// ---------------- launch ----------------

extern "C" void kernel_launch(void* const* d_in, const int* in_sizes, int n_in,
                              void* d_out, int out_size, void* d_ws, size_t ws_size,
                              hipStream_t stream) {
    (void)in_sizes; (void)n_in; (void)out_size; (void)ws_size;
    const float* x      = (const float*)d_in[0];
    const int*   ei     = (const int*)d_in[1];
    const int*   srcv   = ei;
    const int*   dstv   = ei + N_EDGES;
    const int*   batch  = (const int*)d_in[2];
    const float* w1     = (const float*)d_in[3];
    const float* b1     = (const float*)d_in[4];
    const float* bn1_g  = (const float*)d_in[5];
    const float* bn1_b  = (const float*)d_in[6];
    const float* bn1_m  = (const float*)d_in[7];
    const float* bn1_v  = (const float*)d_in[8];
    const float* geps   = (const float*)d_in[9];
    const float* w2     = (const float*)d_in[10];
    const float* b2     = (const float*)d_in[11];
    const float* bn2_g  = (const float*)d_in[12];
    const float* bn2_b  = (const float*)d_in[13];
    const float* bn2_m  = (const float*)d_in[14];
    const float* bn2_v  = (const float*)d_in[15];
    const float* lw1    = (const float*)d_in[16];
    const float* lb1    = (const float*)d_in[17];
    const float* g3     = (const float*)d_in[18];
    const float* b3     = (const float*)d_in[19];
    const float* m3     = (const float*)d_in[20];
    const float* v3     = (const float*)d_in[21];
    const float* lw2    = (const float*)d_in[22];
    const float* lb2    = (const float*)d_in[23];
    float* out = (float*)d_out;

    char* ws = (char*)d_ws;
    __bf16* xb    = (__bf16*)(ws + 0);                 // 25.6 MB (ping)
    __bf16* xb2   = (__bf16*)(ws + 25600000);          // 25.6 MB (pong)
    unsigned int* pairs = (unsigned int*)(ws + 51200000);   // 6.4 MB
    int*    bh    = (int*)   (ws + 57600000);          // 100352
    int*    offs  = (int*)   (ws + 57700352);          // 100352
    int*    bsz   = (int*)   (ws + 57800704);          // 512
    int*    dbh   = (int*)   (ws + 57801216);          // 401408
    int*    doffs = (int*)   (ws + 58202624);          // 401408
    int*    colsz = (int*)   (ws + 58604032);          // 4096
    __bf16* w1S   = (__bf16*)(ws + 76800000);
    __bf16* w2S   = (__bf16*)(ws + 77062144);
    int*    rowp  = (int*)   (ws + 77324288);          // 400004
    int*    perm  = (int*)   (ws + 77724416);          // 400000
    int*    eidx  = (int*)   (ws + 78124416);          // 6.4 MB
    float*  pooled= (float*) (ws + 84524416);          // 262144

    prep_kernel<<<13076, 256, 0, stream>>>(x, w1, w2, xb, w1S, w2S, pooled);

    // CSR build
    count_kernel<<<NBLK, 256, 0, stream>>>(dstv, bh);
    scan_col_kernel<<<NB, 256, 0, stream>>>(bh, offs, bsz);
    bin_place_kernel<<<NBLK, 256, 0, stream>>>(srcv, dstv, offs, bsz, pairs);
    fill2_kernel<<<NB, 256, 0, stream>>>(pairs, bsz, rowp, eidx, dbh);

    // degree sort (descending), deterministic
    dscan_col_kernel<<<1024, 128, 0, stream>>>(dbh, doffs, colsz);
    dplace2_kernel<<<NB, 256, 0, stream>>>(rowp, doffs, colsz, perm);

    int mblocks = (N_NODES + 63) / 64;  // 1563
    __bf16* xin = xb;
    __bf16* xout = xb2;
    for (int l = 0; l < 4; l++) {
        gin_layer<<<mblocks, 256, 0, stream>>>(
            xin, rowp, eidx, perm, w1S + l * 32768, w2S + l * 32768,
            b1 + l * 256, bn1_g + l * 256, bn1_b + l * 256, bn1_m + l * 256, bn1_v + l * 256,
            b2 + l * 128, bn2_g + l * 128, bn2_b + l * 128, bn2_m + l * 128, bn2_v + l * 128,
            geps, l, xout);
        __bf16* t = xin; xin = xout; xout = t;
    }
    // after 4 layers, final x is in xin == xb

    pool_kernel<<<(N_NODES + 63) / 64, 128, 0, stream>>>(xin, batch, pooled);
    final_kernel<<<N_GRAPHS, 128, 0, stream>>>(pooled, lw1, lb1, g3, b3, m3, v3, lw2, lb2, out);
}